// Round 6
// baseline (294.805 us; speedup 1.0000x reference)
//
#include <hip/hip_runtime.h>
#include <hip/hip_bf16.h>
#include <hip/hip_fp16.h>

#define N_NODES 50000
#define N_EDGES 800000
#define DIM 128

#define NBUCK 196      // ceil(N/256) buckets of 256 consecutive dst nodes
#define BCAP  6144     // per-bucket staging capacity (mean 4096, sigma 64)
#define CHUNK 8192     // edges per partition block
#define WCAP  6144     // bucket_fill LDS window capacity

#define CVT_BLOCKS 25000   // 25000*256 == N_NODES*DIM exactly

typedef float floatx4 __attribute__((ext_vector_type(4)));
typedef short shortx8 __attribute__((ext_vector_type(8)));

__device__ __forceinline__ unsigned short f2bf(float f) {
    union { float f; unsigned int u; } c; c.f = f;
    unsigned int u = c.u;
    unsigned int r = (u + 0x7FFFu + ((u >> 16) & 1u)) >> 16;
    return (unsigned short)r;
}
__device__ __forceinline__ float bflo(unsigned int p) {
    union { unsigned int u; float f; } c; c.u = p << 16; return c.f;
}
__device__ __forceinline__ float bfhi(unsigned int p) {
    union { unsigned int u; float f; } c; c.u = p & 0xFFFF0000u; return c.f;
}

// ---------------------------------------------------------------------------
// prep: fused  x->bf16 convert (blocks 0..24999) | zero bcursor (block 25000)
//              | weight pack (blocks 25001..25384)
__global__ __launch_bounds__(256)
void prep_kernel(const float* __restrict__ x, unsigned short* __restrict__ X,
                 const float* __restrict__ wr0, const float* __restrict__ wt0,
                 const float* __restrict__ wr1, const float* __restrict__ wt1,
                 const float* __restrict__ wr2, const float* __restrict__ wt2,
                 unsigned short* __restrict__ Wp, int* __restrict__ bcursor) {
    int b = blockIdx.x;
    if (b < CVT_BLOCKS) {
        int i = b * 256 + threadIdx.x;       // N*DIM is an exact multiple
        X[i] = f2bf(x[i]);
    } else if (b == CVT_BLOCKS) {
        if (threadIdx.x < NBUCK) bcursor[threadIdx.x] = 0;
    } else {
        int id = (b - CVT_BLOCKS - 1) * 256 + threadIdx.x;   // < 3*32768
        int layer = id >> 15;
        int rem = id & 32767;
        int j  = rem & 7;
        int L  = (rem >> 3) & 63;
        int ct = (rem >> 9) & 7;
        int t  = rem >> 12;
        int k = t * 32 + (L >> 4) * 8 + j;
        int c = ct * 16 + (L & 15);
        const float* wr = (layer == 0) ? wr0 : (layer == 1) ? wr1 : wr2;
        const float* wt = (layer == 0) ? wt0 : (layer == 1) ? wt1 : wt2;
        float v = (k < 128) ? wr[k * 128 + c] : wt[(k - 128) * 128 + c];
        Wp[id] = f2bf(v);
    }
}

// Pass 1: bin edges by bucket (dst>>8) through LDS, write contiguous runs per
// bucket into global staging. One 8B entry/edge: {w_fp16<<16|src, dst}.
__global__ __launch_bounds__(256)
void partition_kernel(const int* __restrict__ src, const int* __restrict__ dst,
                      const float* __restrict__ ew,
                      int* __restrict__ bcursor, int2* __restrict__ bstage, int e) {
    __shared__ int2 stage[CHUNK];      // 64 KB
    __shared__ int cnt[NBUCK];
    __shared__ int lbase[NBUCK];
    __shared__ int gbase[NBUCK];
    __shared__ int wsum[4];
    const int tid = threadIdx.x;
    const int e0 = blockIdx.x * CHUNK;
    const int ecnt = min(CHUNK, e - e0);

    for (int i = tid; i < NBUCK; i += 256) cnt[i] = 0;
    __syncthreads();
    for (int i = tid; i < ecnt; i += 256)
        atomicAdd(&cnt[dst[e0 + i] >> 8], 1);
    __syncthreads();

    {
        int v = (tid < NBUCK) ? cnt[tid] : 0;
        int lane = tid & 63, wid = tid >> 6;
        int acc = v;
#pragma unroll
        for (int off = 1; off < 64; off <<= 1) {
            int t = __shfl_up(acc, off, 64);
            if (lane >= off) acc += t;
        }
        if (lane == 63) wsum[wid] = acc;
        __syncthreads();
        int wpref = 0;
        for (int w = 0; w < wid; ++w) wpref += wsum[w];
        int excl = wpref + acc - v;
        if (tid < NBUCK) {
            lbase[tid] = excl;
            gbase[tid] = atomicAdd(&bcursor[tid], v);
            cnt[tid] = 0;            // reuse as local cursor
        }
    }
    __syncthreads();

    for (int i = tid; i < ecnt; i += 256) {
        int d = dst[e0 + i];
        int s = src[e0 + i];
        unsigned int hw = (unsigned int)__half_as_ushort(__float2half(ew[e0 + i]));
        int b = d >> 8;
        int pos = atomicAdd(&cnt[b], 1);
        stage[lbase[b] + pos] = make_int2((int)((hw << 16) | (unsigned int)s), d);
    }
    __syncthreads();

    for (int j = tid; j < ecnt; j += 256) {
        int2 p = stage[j];
        int b = p.y >> 8;
        int gidx = b * BCAP + gbase[b] + (j - lbase[b]);
        bstage[gidx] = p;
    }
}

// Pass 2: per bucket — in-block scan over ALL bucket counts (replaces separate
// bucket_scan kernel), then per-node counts, row_start, LDS scatter, coalesced dump.
__global__ __launch_bounds__(256)
void bucket_fill_kernel(const int2* __restrict__ bstage, const int* __restrict__ bcursor,
                        int* __restrict__ row_start, unsigned int* __restrict__ perm4, int n) {
    __shared__ unsigned int win[WCAP];   // 24 KB
    __shared__ int cnt256[256];
    __shared__ int curs[256];
    __shared__ int wsum[4];
    __shared__ int sbase, scnt;
    const int tid = threadIdx.x;
    const int b = blockIdx.x;
    const int node0 = b << 8;
    const int lane = tid & 63, wid = tid >> 6;

    // in-block exclusive prefix over bucket totals -> this bucket's base
    {
        int v = (tid < NBUCK) ? bcursor[tid] : 0;
        int acc = v;
#pragma unroll
        for (int off = 1; off < 64; off <<= 1) {
            int t = __shfl_up(acc, off, 64);
            if (lane >= off) acc += t;
        }
        if (lane == 63) wsum[wid] = acc;
        __syncthreads();
        int wpref = 0;
        for (int w = 0; w < wid; ++w) wpref += wsum[w];
        int excl = wpref + acc - v;
        if (tid == b) { sbase = excl; scnt = v; }
    }
    __syncthreads();
    const int cntb = scnt;
    const int base = sbase;
    const int2* sp = bstage + (size_t)b * BCAP;

    cnt256[tid] = 0;
    __syncthreads();
    for (int i = tid; i < cntb; i += 256)
        atomicAdd(&cnt256[sp[i].y & 255], 1);
    __syncthreads();

    int v = cnt256[tid];
    int acc = v;
#pragma unroll
    for (int off = 1; off < 64; off <<= 1) {
        int t = __shfl_up(acc, off, 64);
        if (lane >= off) acc += t;
    }
    if (lane == 63) wsum[wid] = acc;
    __syncthreads();
    int wpref = 0;
    for (int w = 0; w < wid; ++w) wpref += wsum[w];
    int excl = wpref + acc - v;
    int node = node0 + tid;
    if (node <= n) row_start[node] = base + excl;
    curs[tid] = excl;
    __syncthreads();

    for (int i = tid; i < cntb; i += 256) {
        int2 p = sp[i];
        int pos = atomicAdd(&curs[p.y & 255], 1);
        win[pos] = (unsigned int)p.x;
    }
    __syncthreads();
    for (int i = tid; i < cntb; i += 256)
        perm4[base + i] = win[i];
}

// gather aggregation: one wave per node, 4 edges in parallel, unroll x4
// (16 edges / 16 gathers in flight). Group g = lane>>4 handles edges t+g,
// t+4+g, ... ; lane loads 16B of the src row at column sl*8.
__global__ __launch_bounds__(256)
void aggregate_bf16(const unsigned short* __restrict__ h, const int* __restrict__ row_start,
                    const unsigned int* __restrict__ perm4,
                    unsigned short* __restrict__ agg, int n) {
    int gwave = (blockIdx.x * 256 + threadIdx.x) >> 6;
    int lane = threadIdx.x & 63;
    if (gwave >= n) return;
    int beg = row_start[gwave];
    int end = row_start[gwave + 1];
    const int g  = lane >> 4;
    const int sl = lane & 15;
    float acc[8];
#pragma unroll
    for (int k = 0; k < 8; ++k) acc[k] = 0.f;

    int t = beg;
    for (; t + 16 <= end; t += 16) {
        unsigned int p0 = perm4[t + g];
        unsigned int p1 = perm4[t + 4 + g];
        unsigned int p2 = perm4[t + 8 + g];
        unsigned int p3 = perm4[t + 12 + g];
        int s0 = p0 & 0xFFFF, s1 = p1 & 0xFFFF, s2 = p2 & 0xFFFF, s3 = p3 & 0xFFFF;
        uint4 v0 = *(const uint4*)(h + (size_t)s0 * DIM + sl * 8);
        uint4 v1 = *(const uint4*)(h + (size_t)s1 * DIM + sl * 8);
        uint4 v2 = *(const uint4*)(h + (size_t)s2 * DIM + sl * 8);
        uint4 v3 = *(const uint4*)(h + (size_t)s3 * DIM + sl * 8);
        float w0 = __half2float(__ushort_as_half((unsigned short)(p0 >> 16)));
        float w1 = __half2float(__ushort_as_half((unsigned short)(p1 >> 16)));
        float w2 = __half2float(__ushort_as_half((unsigned short)(p2 >> 16)));
        float w3 = __half2float(__ushort_as_half((unsigned short)(p3 >> 16)));
        acc[0] += w0 * bflo(v0.x); acc[1] += w0 * bfhi(v0.x);
        acc[2] += w0 * bflo(v0.y); acc[3] += w0 * bfhi(v0.y);
        acc[4] += w0 * bflo(v0.z); acc[5] += w0 * bfhi(v0.z);
        acc[6] += w0 * bflo(v0.w); acc[7] += w0 * bfhi(v0.w);
        acc[0] += w1 * bflo(v1.x); acc[1] += w1 * bfhi(v1.x);
        acc[2] += w1 * bflo(v1.y); acc[3] += w1 * bfhi(v1.y);
        acc[4] += w1 * bflo(v1.z); acc[5] += w1 * bfhi(v1.z);
        acc[6] += w1 * bflo(v1.w); acc[7] += w1 * bfhi(v1.w);
        acc[0] += w2 * bflo(v2.x); acc[1] += w2 * bfhi(v2.x);
        acc[2] += w2 * bflo(v2.y); acc[3] += w2 * bfhi(v2.y);
        acc[4] += w2 * bflo(v2.z); acc[5] += w2 * bfhi(v2.z);
        acc[6] += w2 * bflo(v2.w); acc[7] += w2 * bfhi(v2.w);
        acc[0] += w3 * bflo(v3.x); acc[1] += w3 * bfhi(v3.x);
        acc[2] += w3 * bflo(v3.y); acc[3] += w3 * bfhi(v3.y);
        acc[4] += w3 * bflo(v3.z); acc[5] += w3 * bfhi(v3.z);
        acc[6] += w3 * bflo(v3.w); acc[7] += w3 * bfhi(v3.w);
    }
    for (; t < end; t += 4) {
        int idx = t + g;
        unsigned int p0 = (idx < end) ? perm4[idx] : 0;  // p=0 -> src 0, w=+0
        int s0 = p0 & 0xFFFF;
        float w0 = __half2float(__ushort_as_half((unsigned short)(p0 >> 16)));
        uint4 v0 = *(const uint4*)(h + (size_t)s0 * DIM + sl * 8);
        acc[0] += w0 * bflo(v0.x); acc[1] += w0 * bfhi(v0.x);
        acc[2] += w0 * bflo(v0.y); acc[3] += w0 * bfhi(v0.y);
        acc[4] += w0 * bflo(v0.z); acc[5] += w0 * bfhi(v0.z);
        acc[6] += w0 * bflo(v0.w); acc[7] += w0 * bfhi(v0.w);
    }
#pragma unroll
    for (int k = 0; k < 8; ++k) {
        acc[k] += __shfl_xor(acc[k], 16, 64);
        acc[k] += __shfl_xor(acc[k], 32, 64);
    }
    if (lane < 16) {
        uint4 r;
        r.x = (unsigned int)f2bf(acc[0]) | ((unsigned int)f2bf(acc[1]) << 16);
        r.y = (unsigned int)f2bf(acc[2]) | ((unsigned int)f2bf(acc[3]) << 16);
        r.z = (unsigned int)f2bf(acc[4]) | ((unsigned int)f2bf(acc[5]) << 16);
        r.w = (unsigned int)f2bf(acc[6]) | ((unsigned int)f2bf(acc[7]) << 16);
        *(uint4*)(agg + (size_t)gwave * DIM + sl * 8) = r;
    }
}

// MFMA GEMM: C[n,128] = [G | H] (n x 256, bf16) @ W (256x128, bf16 pre-packed) + bias
__global__ __launch_bounds__(256)
void gemm_mfma(const unsigned short* __restrict__ G, const unsigned short* __restrict__ H,
               const unsigned short* __restrict__ Wp, const float* __restrict__ bias,
               float* __restrict__ outF, unsigned short* __restrict__ outB,
               int n, int relu) {
    const int L   = threadIdx.x & 63;
    const int wid = threadIdx.x >> 6;
    const int m = L & 15, q = L >> 4;
    const int rowT = blockIdx.x * 128 + wid * 32;
    int r0 = rowT + m;
    int r1 = rowT + 16 + m;
    int rr0 = (r0 < n) ? r0 : (n - 1);
    int rr1 = (r1 < n) ? r1 : (n - 1);
    const int ko = q * 8;

    floatx4 acc[2][8];
#pragma unroll
    for (int mi = 0; mi < 2; ++mi)
#pragma unroll
        for (int ct = 0; ct < 8; ++ct) acc[mi][ct] = (floatx4){0.f, 0.f, 0.f, 0.f};

#pragma unroll
    for (int t = 0; t < 8; ++t) {
        const unsigned short* A = (t < 4) ? G : H;
        const int kk = (t & 3) * 32 + ko;
        shortx8 a0 = *(const shortx8*)(A + (size_t)rr0 * DIM + kk);
        shortx8 a1 = *(const shortx8*)(A + (size_t)rr1 * DIM + kk);
        const unsigned short* wp = Wp + (size_t)t * 4096 + L * 8;
#pragma unroll
        for (int ct = 0; ct < 8; ++ct) {
            shortx8 b = *(const shortx8*)(wp + ct * 512);
            acc[0][ct] = __builtin_amdgcn_mfma_f32_16x16x32_bf16(a0, b, acc[0][ct], 0, 0, 0);
            acc[1][ct] = __builtin_amdgcn_mfma_f32_16x16x32_bf16(a1, b, acc[1][ct], 0, 0, 0);
        }
    }

#pragma unroll
    for (int ct = 0; ct < 8; ++ct) {
        int col = ct * 16 + m;
        float bv = bias[col];
#pragma unroll
        for (int mi = 0; mi < 2; ++mi) {
#pragma unroll
            for (int i = 0; i < 4; ++i) {
                int row = rowT + mi * 16 + q * 4 + i;
                if (row < n) {
                    float v = acc[mi][ct][i] + bv;
                    if (relu) v = fmaxf(v, 0.f);
                    if (outF) outF[(size_t)row * DIM + col] = v;
                    else      outB[(size_t)row * DIM + col] = f2bf(v);
                }
            }
        }
    }
}

extern "C" void kernel_launch(void* const* d_in, const int* in_sizes, int n_in,
                              void* d_out, int out_size, void* d_ws, size_t ws_size,
                              hipStream_t stream) {
    const int N = N_NODES, E = N_EDGES;

    const float* x   = (const float*)d_in[0];
    const int*   ei  = (const int*)d_in[1];
    const float* ea  = (const float*)d_in[2];
    const float* wr0 = (const float*)d_in[3];
    const float* br0 = (const float*)d_in[4];
    const float* wt0 = (const float*)d_in[5];
    const float* wr1 = (const float*)d_in[6];
    const float* br1 = (const float*)d_in[7];
    const float* wt1 = (const float*)d_in[8];
    const float* wr2 = (const float*)d_in[9];
    const float* br2 = (const float*)d_in[10];
    const float* wt2 = (const float*)d_in[11];
    const int* srcI = ei;
    const int* dstI = ei + E;
    float* out = (float*)d_out;

    // workspace layout (bstage first for 8B alignment)
    int2* bstage = (int2*)d_ws;                              // NBUCK*BCAP int2 (9.6MB)
    unsigned short* X  = (unsigned short*)(bstage + (size_t)NBUCK * BCAP);  // N*128 bf16
    unsigned short* H  = X + (size_t)N * DIM;                // N*128 bf16
    unsigned short* G  = H + (size_t)N * DIM;                // N*128 bf16
    unsigned short* Wp = G + (size_t)N * DIM;                // 3*32768 bf16
    unsigned int* perm4 = (unsigned int*)(Wp + 3 * 32768);   // E u32
    int* bcursor = (int*)(perm4 + E);                        // NBUCK i32
    int* rowst   = bcursor + NBUCK;                          // N+1 i32

    // prep (cvt + zero + pack) and CSR build via binned counting sort
    prep_kernel<<<CVT_BLOCKS + 1 + 384, 256, 0, stream>>>(x, X, wr0, wt0, wr1, wt1, wr2, wt2, Wp, bcursor);
    partition_kernel<<<(E + CHUNK - 1) / CHUNK, 256, 0, stream>>>(srcI, dstI, ea, bcursor, bstage, E);
    bucket_fill_kernel<<<NBUCK, 256, 0, stream>>>(bstage, bcursor, rowst, perm4, N);

    const int aggGrid  = (N + 3) / 4;            // 4 waves/block, 1 wave/node
    const int gemmGrid = (N + 127) / 128;        // 128 rows/block

    // layer 0
    aggregate_bf16<<<aggGrid, 256, 0, stream>>>(X, rowst, perm4, G, N);
    gemm_mfma<<<gemmGrid, 256, 0, stream>>>(G, X, Wp, br0, nullptr, H, N, 1);
    // layer 1 (in-place H: each block reads only the rows it writes)
    aggregate_bf16<<<aggGrid, 256, 0, stream>>>(H, rowst, perm4, G, N);
    gemm_mfma<<<gemmGrid, 256, 0, stream>>>(G, H, Wp + 32768, br1, nullptr, H, N, 1);
    // layer 2 -> fp32 out
    aggregate_bf16<<<aggGrid, 256, 0, stream>>>(H, rowst, perm4, G, N);
    gemm_mfma<<<gemmGrid, 256, 0, stream>>>(G, H, Wp + 65536, br2, out, nullptr, N, 0);
}

// Round 7
// 281.514 us; speedup vs baseline: 1.0472x; 1.0472x over previous
//
#include <hip/hip_runtime.h>
#include <hip/hip_bf16.h>
#include <hip/hip_fp16.h>

#define N_NODES 50000
#define N_EDGES 800000
#define DIM 128

#define NBUCK 196      // ceil(N/256) buckets of 256 consecutive dst nodes
#define BCAP  6144     // per-bucket staging capacity (mean 4096, sigma 64)
#define CHUNK 8192     // edges per partition block
#define WCAP  6144     // bucket_fill LDS window capacity

#define CVT_BLOCKS 25000   // 25000*256 == N_NODES*DIM exactly

#define LDSROW 136     // Gs row stride in shorts (272 B: 2-way bank alias = free)

typedef float floatx4 __attribute__((ext_vector_type(4)));
typedef short shortx8 __attribute__((ext_vector_type(8)));

__device__ __forceinline__ unsigned short f2bf(float f) {
    union { float f; unsigned int u; } c; c.f = f;
    unsigned int u = c.u;
    unsigned int r = (u + 0x7FFFu + ((u >> 16) & 1u)) >> 16;
    return (unsigned short)r;
}
__device__ __forceinline__ float bflo(unsigned int p) {
    union { unsigned int u; float f; } c; c.u = p << 16; return c.f;
}
__device__ __forceinline__ float bfhi(unsigned int p) {
    union { unsigned int u; float f; } c; c.u = p & 0xFFFF0000u; return c.f;
}

// ---------------------------------------------------------------------------
// prep: fused  x->bf16 convert | zero bcursor | weight pack
__global__ __launch_bounds__(256)
void prep_kernel(const float* __restrict__ x, unsigned short* __restrict__ X,
                 const float* __restrict__ wr0, const float* __restrict__ wt0,
                 const float* __restrict__ wr1, const float* __restrict__ wt1,
                 const float* __restrict__ wr2, const float* __restrict__ wt2,
                 unsigned short* __restrict__ Wp, int* __restrict__ bcursor) {
    int b = blockIdx.x;
    if (b < CVT_BLOCKS) {
        int i = b * 256 + threadIdx.x;       // N*DIM is an exact multiple
        X[i] = f2bf(x[i]);
    } else if (b == CVT_BLOCKS) {
        if (threadIdx.x < NBUCK) bcursor[threadIdx.x] = 0;
    } else {
        int id = (b - CVT_BLOCKS - 1) * 256 + threadIdx.x;   // < 3*32768
        int layer = id >> 15;
        int rem = id & 32767;
        int j  = rem & 7;
        int L  = (rem >> 3) & 63;
        int ct = (rem >> 9) & 7;
        int t  = rem >> 12;
        int k = t * 32 + (L >> 4) * 8 + j;
        int c = ct * 16 + (L & 15);
        const float* wr = (layer == 0) ? wr0 : (layer == 1) ? wr1 : wr2;
        const float* wt = (layer == 0) ? wt0 : (layer == 1) ? wt1 : wt2;
        float v = (k < 128) ? wr[k * 128 + c] : wt[(k - 128) * 128 + c];
        Wp[id] = f2bf(v);
    }
}

// Pass 1: bin edges by bucket (dst>>8) through LDS, contiguous runs to staging.
__global__ __launch_bounds__(256)
void partition_kernel(const int* __restrict__ src, const int* __restrict__ dst,
                      const float* __restrict__ ew,
                      int* __restrict__ bcursor, int2* __restrict__ bstage, int e) {
    __shared__ int2 stage[CHUNK];      // 64 KB
    __shared__ int cnt[NBUCK];
    __shared__ int lbase[NBUCK];
    __shared__ int gbase[NBUCK];
    __shared__ int wsum[4];
    const int tid = threadIdx.x;
    const int e0 = blockIdx.x * CHUNK;
    const int ecnt = min(CHUNK, e - e0);

    for (int i = tid; i < NBUCK; i += 256) cnt[i] = 0;
    __syncthreads();
    for (int i = tid; i < ecnt; i += 256)
        atomicAdd(&cnt[dst[e0 + i] >> 8], 1);
    __syncthreads();

    {
        int v = (tid < NBUCK) ? cnt[tid] : 0;
        int lane = tid & 63, wid = tid >> 6;
        int acc = v;
#pragma unroll
        for (int off = 1; off < 64; off <<= 1) {
            int t = __shfl_up(acc, off, 64);
            if (lane >= off) acc += t;
        }
        if (lane == 63) wsum[wid] = acc;
        __syncthreads();
        int wpref = 0;
        for (int w = 0; w < wid; ++w) wpref += wsum[w];
        int excl = wpref + acc - v;
        if (tid < NBUCK) {
            lbase[tid] = excl;
            gbase[tid] = atomicAdd(&bcursor[tid], v);
            cnt[tid] = 0;            // reuse as local cursor
        }
    }
    __syncthreads();

    for (int i = tid; i < ecnt; i += 256) {
        int d = dst[e0 + i];
        int s = src[e0 + i];
        unsigned int hw = (unsigned int)__half_as_ushort(__float2half(ew[e0 + i]));
        int b = d >> 8;
        int pos = atomicAdd(&cnt[b], 1);
        stage[lbase[b] + pos] = make_int2((int)((hw << 16) | (unsigned int)s), d);
    }
    __syncthreads();

    for (int j = tid; j < ecnt; j += 256) {
        int2 p = stage[j];
        int b = p.y >> 8;
        int gidx = b * BCAP + gbase[b] + (j - lbase[b]);
        bstage[gidx] = p;
    }
}

// Pass 2: per bucket — in-block scan of bucket totals, per-node counts,
// row_start, LDS scatter, coalesced dump.
__global__ __launch_bounds__(256)
void bucket_fill_kernel(const int2* __restrict__ bstage, const int* __restrict__ bcursor,
                        int* __restrict__ row_start, unsigned int* __restrict__ perm4, int n) {
    __shared__ unsigned int win[WCAP];   // 24 KB
    __shared__ int cnt256[256];
    __shared__ int curs[256];
    __shared__ int wsum[4];
    __shared__ int sbase, scnt;
    const int tid = threadIdx.x;
    const int b = blockIdx.x;
    const int node0 = b << 8;
    const int lane = tid & 63, wid = tid >> 6;

    {
        int v = (tid < NBUCK) ? bcursor[tid] : 0;
        int acc = v;
#pragma unroll
        for (int off = 1; off < 64; off <<= 1) {
            int t = __shfl_up(acc, off, 64);
            if (lane >= off) acc += t;
        }
        if (lane == 63) wsum[wid] = acc;
        __syncthreads();
        int wpref = 0;
        for (int w = 0; w < wid; ++w) wpref += wsum[w];
        int excl = wpref + acc - v;
        if (tid == b) { sbase = excl; scnt = v; }
    }
    __syncthreads();
    const int cntb = scnt;
    const int base = sbase;
    const int2* sp = bstage + (size_t)b * BCAP;

    cnt256[tid] = 0;
    __syncthreads();
    for (int i = tid; i < cntb; i += 256)
        atomicAdd(&cnt256[sp[i].y & 255], 1);
    __syncthreads();

    int v = cnt256[tid];
    int acc = v;
#pragma unroll
    for (int off = 1; off < 64; off <<= 1) {
        int t = __shfl_up(acc, off, 64);
        if (lane >= off) acc += t;
    }
    if (lane == 63) wsum[wid] = acc;
    __syncthreads();
    int wpref = 0;
    for (int w = 0; w < wid; ++w) wpref += wsum[w];
    int excl = wpref + acc - v;
    int node = node0 + tid;
    if (node <= n) row_start[node] = base + excl;
    curs[tid] = excl;
    __syncthreads();

    for (int i = tid; i < cntb; i += 256) {
        int2 p = sp[i];
        int pos = atomicAdd(&curs[p.y & 255], 1);
        win[pos] = (unsigned int)p.x;
    }
    __syncthreads();
    for (int i = tid; i < cntb; i += 256)
        perm4[base + i] = win[i];
}

// ---------------------------------------------------------------------------
// Fused layer: block = 64 rows, 256 threads (4 waves), NO __syncthreads.
// Phase 1: wave w aggregates nodes [rowT+16w, rowT+16w+16) into its own LDS
//          rows (4 edges in parallel: group g=lane>>4, lane reads 16B of row).
// Phase 2: same wave MFMAs its 16 rows: C = [Gs | h] @ Wp + bias.
// Cross-block safety: gathers read h (prev layer), output goes to a DIFFERENT
// buffer (ping-pong) — no read/write overlap between blocks.
__global__ __launch_bounds__(256)
void fused_layer(const unsigned short* __restrict__ h, const int* __restrict__ row_start,
                 const unsigned int* __restrict__ perm4, const unsigned short* __restrict__ Wp,
                 const float* __restrict__ bias, float* __restrict__ outF,
                 unsigned short* __restrict__ outB, int n, int relu) {
    __shared__ unsigned short Gs[64 * LDSROW];   // 17.4 KB
    const int tid  = threadIdx.x;
    const int lane = tid & 63;
    const int wid  = tid >> 6;
    const int g  = lane >> 4;      // group / q
    const int sl = lane & 15;      // col-chunk / m
    const int rowT = blockIdx.x * 64;
    const int nodeBase = rowT + wid * 16;

    // row_start window for this wave's 16 nodes (one load, distribute by shfl)
    int rs = 0;
    if (lane < 17) {
        int idx = nodeBase + lane;
        rs = row_start[idx <= n ? idx : n];
    }

    // ---- phase 1: aggregate 16 nodes into LDS ----
    for (int nd = 0; nd < 16; ++nd) {
        if (nodeBase + nd >= n) break;           // wave-uniform
        int beg = __shfl(rs, nd, 64);
        int end = __shfl(rs, nd + 1, 64);
        float acc[8];
#pragma unroll
        for (int k = 0; k < 8; ++k) acc[k] = 0.f;
        for (int t = beg; t < end; t += 16) {
            int i0 = t + g, i1 = t + 4 + g, i2 = t + 8 + g, i3 = t + 12 + g;
            unsigned int p0 = (i0 < end) ? perm4[i0] : 0;   // p=0 -> src 0, w=+0
            unsigned int p1 = (i1 < end) ? perm4[i1] : 0;
            unsigned int p2 = (i2 < end) ? perm4[i2] : 0;
            unsigned int p3 = (i3 < end) ? perm4[i3] : 0;
            int s0 = p0 & 0xFFFF, s1 = p1 & 0xFFFF, s2 = p2 & 0xFFFF, s3 = p3 & 0xFFFF;
            uint4 v0 = *(const uint4*)(h + (size_t)s0 * DIM + sl * 8);
            uint4 v1 = *(const uint4*)(h + (size_t)s1 * DIM + sl * 8);
            uint4 v2 = *(const uint4*)(h + (size_t)s2 * DIM + sl * 8);
            uint4 v3 = *(const uint4*)(h + (size_t)s3 * DIM + sl * 8);
            float w0 = __half2float(__ushort_as_half((unsigned short)(p0 >> 16)));
            float w1 = __half2float(__ushort_as_half((unsigned short)(p1 >> 16)));
            float w2 = __half2float(__ushort_as_half((unsigned short)(p2 >> 16)));
            float w3 = __half2float(__ushort_as_half((unsigned short)(p3 >> 16)));
            acc[0] += w0 * bflo(v0.x); acc[1] += w0 * bfhi(v0.x);
            acc[2] += w0 * bflo(v0.y); acc[3] += w0 * bfhi(v0.y);
            acc[4] += w0 * bflo(v0.z); acc[5] += w0 * bfhi(v0.z);
            acc[6] += w0 * bflo(v0.w); acc[7] += w0 * bfhi(v0.w);
            acc[0] += w1 * bflo(v1.x); acc[1] += w1 * bfhi(v1.x);
            acc[2] += w1 * bflo(v1.y); acc[3] += w1 * bfhi(v1.y);
            acc[4] += w1 * bflo(v1.z); acc[5] += w1 * bfhi(v1.z);
            acc[6] += w1 * bflo(v1.w); acc[7] += w1 * bfhi(v1.w);
            acc[0] += w2 * bflo(v2.x); acc[1] += w2 * bfhi(v2.x);
            acc[2] += w2 * bflo(v2.y); acc[3] += w2 * bfhi(v2.y);
            acc[4] += w2 * bflo(v2.z); acc[5] += w2 * bfhi(v2.z);
            acc[6] += w2 * bflo(v2.w); acc[7] += w2 * bfhi(v2.w);
            acc[0] += w3 * bflo(v3.x); acc[1] += w3 * bfhi(v3.x);
            acc[2] += w3 * bflo(v3.y); acc[3] += w3 * bfhi(v3.y);
            acc[4] += w3 * bflo(v3.z); acc[5] += w3 * bfhi(v3.z);
            acc[6] += w3 * bflo(v3.w); acc[7] += w3 * bfhi(v3.w);
        }
#pragma unroll
        for (int k = 0; k < 8; ++k) {
            acc[k] += __shfl_xor(acc[k], 16, 64);
            acc[k] += __shfl_xor(acc[k], 32, 64);
        }
        if (lane < 16) {
            uint4 r;
            r.x = (unsigned int)f2bf(acc[0]) | ((unsigned int)f2bf(acc[1]) << 16);
            r.y = (unsigned int)f2bf(acc[2]) | ((unsigned int)f2bf(acc[3]) << 16);
            r.z = (unsigned int)f2bf(acc[4]) | ((unsigned int)f2bf(acc[5]) << 16);
            r.w = (unsigned int)f2bf(acc[6]) | ((unsigned int)f2bf(acc[7]) << 16);
            *(uint4*)(&Gs[(wid * 16 + nd) * LDSROW + sl * 8]) = r;
        }
    }
    // no __syncthreads: each wave reads back only the LDS rows it wrote
    // (lgkmcnt orders ds_write -> ds_read within the wave)

    // ---- phase 2: MFMA this wave's 16 rows ----
    floatx4 acc2[8];
#pragma unroll
    for (int ct = 0; ct < 8; ++ct) acc2[ct] = (floatx4){0.f, 0.f, 0.f, 0.f};

    int rGlob = nodeBase + sl;
    int rr = (rGlob < n) ? rGlob : (n - 1);
    const int ko = g * 8;
#pragma unroll
    for (int t = 0; t < 8; ++t) {
        shortx8 a;
        if (t < 4)
            a = *(const shortx8*)(&Gs[(wid * 16 + sl) * LDSROW + t * 32 + ko]);
        else
            a = *(const shortx8*)(h + (size_t)rr * DIM + (t - 4) * 32 + ko);
        const unsigned short* wp = Wp + (size_t)t * 4096 + lane * 8;
#pragma unroll
        for (int ct = 0; ct < 8; ++ct) {
            shortx8 b = *(const shortx8*)(wp + ct * 512);
            acc2[ct] = __builtin_amdgcn_mfma_f32_16x16x32_bf16(a, b, acc2[ct], 0, 0, 0);
        }
    }

#pragma unroll
    for (int ct = 0; ct < 8; ++ct) {
        int col = ct * 16 + sl;
        float bv = bias[col];
#pragma unroll
        for (int i = 0; i < 4; ++i) {
            int row = nodeBase + g * 4 + i;
            if (row < n) {
                float v = acc2[ct][i] + bv;
                if (relu) v = fmaxf(v, 0.f);
                if (outF) outF[(size_t)row * DIM + col] = v;
                else      outB[(size_t)row * DIM + col] = f2bf(v);
            }
        }
    }
}

extern "C" void kernel_launch(void* const* d_in, const int* in_sizes, int n_in,
                              void* d_out, int out_size, void* d_ws, size_t ws_size,
                              hipStream_t stream) {
    const int N = N_NODES, E = N_EDGES;

    const float* x   = (const float*)d_in[0];
    const int*   ei  = (const int*)d_in[1];
    const float* ea  = (const float*)d_in[2];
    const float* wr0 = (const float*)d_in[3];
    const float* br0 = (const float*)d_in[4];
    const float* wt0 = (const float*)d_in[5];
    const float* wr1 = (const float*)d_in[6];
    const float* br1 = (const float*)d_in[7];
    const float* wt1 = (const float*)d_in[8];
    const float* wr2 = (const float*)d_in[9];
    const float* br2 = (const float*)d_in[10];
    const float* wt2 = (const float*)d_in[11];
    const int* srcI = ei;
    const int* dstI = ei + E;
    float* out = (float*)d_out;

    // workspace layout (bstage first for 8B alignment)
    int2* bstage = (int2*)d_ws;                              // NBUCK*BCAP int2 (9.6MB)
    unsigned short* X  = (unsigned short*)(bstage + (size_t)NBUCK * BCAP);  // N*128 bf16
    unsigned short* H1 = X + (size_t)N * DIM;                // N*128 bf16
    unsigned short* H2 = H1 + (size_t)N * DIM;               // N*128 bf16
    unsigned short* Wp = H2 + (size_t)N * DIM;               // 3*32768 bf16
    unsigned int* perm4 = (unsigned int*)(Wp + 3 * 32768);   // E u32
    int* bcursor = (int*)(perm4 + E);                        // NBUCK i32
    int* rowst   = bcursor + NBUCK;                          // N+1 i32

    // prep (cvt + zero + pack) and CSR build via binned counting sort
    prep_kernel<<<CVT_BLOCKS + 1 + 384, 256, 0, stream>>>(x, X, wr0, wt0, wr1, wt1, wr2, wt2, Wp, bcursor);
    partition_kernel<<<(E + CHUNK - 1) / CHUNK, 256, 0, stream>>>(srcI, dstI, ea, bcursor, bstage, E);
    bucket_fill_kernel<<<NBUCK, 256, 0, stream>>>(bstage, bcursor, rowst, perm4, N);

    const int fusedGrid = (N + 63) / 64;     // 782 blocks, 64 rows each

    // ping-pong h buffers: gathers read prev layer, writes go to a new buffer
    fused_layer<<<fusedGrid, 256, 0, stream>>>(X,  rowst, perm4, Wp,         br0, nullptr, H1, N, 1);
    fused_layer<<<fusedGrid, 256, 0, stream>>>(H1, rowst, perm4, Wp + 32768, br1, nullptr, H2, N, 1);
    fused_layer<<<fusedGrid, 256, 0, stream>>>(H2, rowst, perm4, Wp + 65536, br2, out, nullptr, N, 0);
}

// Round 8
// 260.140 us; speedup vs baseline: 1.1333x; 1.0822x over previous
//
#include <hip/hip_runtime.h>
#include <hip/hip_bf16.h>
#include <hip/hip_fp16.h>

#define N_NODES 50000
#define N_EDGES 800000
#define DIM 128

#define NBUCK 196      // ceil(N/256) buckets of 256 consecutive dst nodes
#define BCAP  6144     // per-bucket staging capacity (mean 4096, sigma 64)
#define CHUNK 8192     // edges per partition block
#define WCAP  6144     // bucket_fill LDS window capacity

#define CVT_BLOCKS 25000   // 25000*256 == N_NODES*DIM exactly

#define LDSROW 136     // Gs row stride in shorts (272 B: 2-way bank alias = free)

typedef float floatx4 __attribute__((ext_vector_type(4)));
typedef short shortx8 __attribute__((ext_vector_type(8)));

__device__ __forceinline__ unsigned short f2bf(float f) {
    union { float f; unsigned int u; } c; c.f = f;
    unsigned int u = c.u;
    unsigned int r = (u + 0x7FFFu + ((u >> 16) & 1u)) >> 16;
    return (unsigned short)r;
}
__device__ __forceinline__ float bflo(unsigned int p) {
    union { unsigned int u; float f; } c; c.u = p << 16; return c.f;
}
__device__ __forceinline__ float bfhi(unsigned int p) {
    union { unsigned int u; float f; } c; c.u = p & 0xFFFF0000u; return c.f;
}

// ---------------------------------------------------------------------------
// prep: fused  x->bf16 convert | zero bcursor | weight pack
__global__ __launch_bounds__(256)
void prep_kernel(const float* __restrict__ x, unsigned short* __restrict__ X,
                 const float* __restrict__ wr0, const float* __restrict__ wt0,
                 const float* __restrict__ wr1, const float* __restrict__ wt1,
                 const float* __restrict__ wr2, const float* __restrict__ wt2,
                 unsigned short* __restrict__ Wp, int* __restrict__ bcursor) {
    int b = blockIdx.x;
    if (b < CVT_BLOCKS) {
        int i = b * 256 + threadIdx.x;       // N*DIM is an exact multiple
        X[i] = f2bf(x[i]);
    } else if (b == CVT_BLOCKS) {
        if (threadIdx.x < NBUCK) bcursor[threadIdx.x] = 0;
    } else {
        int id = (b - CVT_BLOCKS - 1) * 256 + threadIdx.x;   // < 3*32768
        int layer = id >> 15;
        int rem = id & 32767;
        int j  = rem & 7;
        int L  = (rem >> 3) & 63;
        int ct = (rem >> 9) & 7;
        int t  = rem >> 12;
        int k = t * 32 + (L >> 4) * 8 + j;
        int c = ct * 16 + (L & 15);
        const float* wr = (layer == 0) ? wr0 : (layer == 1) ? wr1 : wr2;
        const float* wt = (layer == 0) ? wt0 : (layer == 1) ? wt1 : wt2;
        float v = (k < 128) ? wr[k * 128 + c] : wt[(k - 128) * 128 + c];
        Wp[id] = f2bf(v);
    }
}

// Pass 1: bin edges by bucket (dst>>8) through LDS, contiguous runs to staging.
__global__ __launch_bounds__(256)
void partition_kernel(const int* __restrict__ src, const int* __restrict__ dst,
                      const float* __restrict__ ew,
                      int* __restrict__ bcursor, int2* __restrict__ bstage, int e) {
    __shared__ int2 stage[CHUNK];      // 64 KB
    __shared__ int cnt[NBUCK];
    __shared__ int lbase[NBUCK];
    __shared__ int gbase[NBUCK];
    __shared__ int wsum[4];
    const int tid = threadIdx.x;
    const int e0 = blockIdx.x * CHUNK;
    const int ecnt = min(CHUNK, e - e0);

    for (int i = tid; i < NBUCK; i += 256) cnt[i] = 0;
    __syncthreads();
    for (int i = tid; i < ecnt; i += 256)
        atomicAdd(&cnt[dst[e0 + i] >> 8], 1);
    __syncthreads();

    {
        int v = (tid < NBUCK) ? cnt[tid] : 0;
        int lane = tid & 63, wid = tid >> 6;
        int acc = v;
#pragma unroll
        for (int off = 1; off < 64; off <<= 1) {
            int t = __shfl_up(acc, off, 64);
            if (lane >= off) acc += t;
        }
        if (lane == 63) wsum[wid] = acc;
        __syncthreads();
        int wpref = 0;
        for (int w = 0; w < wid; ++w) wpref += wsum[w];
        int excl = wpref + acc - v;
        if (tid < NBUCK) {
            lbase[tid] = excl;
            gbase[tid] = atomicAdd(&bcursor[tid], v);
            cnt[tid] = 0;            // reuse as local cursor
        }
    }
    __syncthreads();

    for (int i = tid; i < ecnt; i += 256) {
        int d = dst[e0 + i];
        int s = src[e0 + i];
        unsigned int hw = (unsigned int)__half_as_ushort(__float2half(ew[e0 + i]));
        int b = d >> 8;
        int pos = atomicAdd(&cnt[b], 1);
        stage[lbase[b] + pos] = make_int2((int)((hw << 16) | (unsigned int)s), d);
    }
    __syncthreads();

    for (int j = tid; j < ecnt; j += 256) {
        int2 p = stage[j];
        int b = p.y >> 8;
        int gidx = b * BCAP + gbase[b] + (j - lbase[b]);
        bstage[gidx] = p;
    }
}

// Pass 2: per bucket — in-block scan of bucket totals, per-node counts,
// row_start, LDS scatter, coalesced dump.
__global__ __launch_bounds__(256)
void bucket_fill_kernel(const int2* __restrict__ bstage, const int* __restrict__ bcursor,
                        int* __restrict__ row_start, unsigned int* __restrict__ perm4, int n) {
    __shared__ unsigned int win[WCAP];   // 24 KB
    __shared__ int cnt256[256];
    __shared__ int curs[256];
    __shared__ int wsum[4];
    __shared__ int sbase, scnt;
    const int tid = threadIdx.x;
    const int b = blockIdx.x;
    const int node0 = b << 8;
    const int lane = tid & 63, wid = tid >> 6;

    {
        int v = (tid < NBUCK) ? bcursor[tid] : 0;
        int acc = v;
#pragma unroll
        for (int off = 1; off < 64; off <<= 1) {
            int t = __shfl_up(acc, off, 64);
            if (lane >= off) acc += t;
        }
        if (lane == 63) wsum[wid] = acc;
        __syncthreads();
        int wpref = 0;
        for (int w = 0; w < wid; ++w) wpref += wsum[w];
        int excl = wpref + acc - v;
        if (tid == b) { sbase = excl; scnt = v; }
    }
    __syncthreads();
    const int cntb = scnt;
    const int base = sbase;
    const int2* sp = bstage + (size_t)b * BCAP;

    cnt256[tid] = 0;
    __syncthreads();
    for (int i = tid; i < cntb; i += 256)
        atomicAdd(&cnt256[sp[i].y & 255], 1);
    __syncthreads();

    int v = cnt256[tid];
    int acc = v;
#pragma unroll
    for (int off = 1; off < 64; off <<= 1) {
        int t = __shfl_up(acc, off, 64);
        if (lane >= off) acc += t;
    }
    if (lane == 63) wsum[wid] = acc;
    __syncthreads();
    int wpref = 0;
    for (int w = 0; w < wid; ++w) wpref += wsum[w];
    int excl = wpref + acc - v;
    int node = node0 + tid;
    if (node <= n) row_start[node] = base + excl;
    curs[tid] = excl;
    __syncthreads();

    for (int i = tid; i < cntb; i += 256) {
        int2 p = sp[i];
        int pos = atomicAdd(&curs[p.y & 255], 1);
        win[pos] = (unsigned int)p.x;
    }
    __syncthreads();
    for (int i = tid; i < cntb; i += 256)
        perm4[base + i] = win[i];
}

// ---------------------------------------------------------------------------
// Fused layer v2: block = 32 rows, 256 threads (4 waves), ONE barrier.
// Phase 1: wave w aggregates 8 nodes [rowT+8w, rowT+8w+8) into LDS rows
//          (4 edges in parallel: group g=lane>>4, lane reads 16B of row).
// Phase 2: wave w MFMAs row-group rg=w>>1 (16 rows) x col-half ch=w&1 (64 cols);
//          A from LDS (t<4) / h global (t>=4), B from pre-packed Wp.
// 1563 blocks (~6/CU) x 4 waves -> ~24 waves/CU for gather-latency hiding.
__global__ __launch_bounds__(256, 6)
void fused_layer(const unsigned short* __restrict__ h, const int* __restrict__ row_start,
                 const unsigned int* __restrict__ perm4, const unsigned short* __restrict__ Wp,
                 const float* __restrict__ bias, float* __restrict__ outF,
                 unsigned short* __restrict__ outB, int n, int relu) {
    __shared__ unsigned short Gs[32 * LDSROW];   // 8.7 KB
    const int tid  = threadIdx.x;
    const int lane = tid & 63;
    const int wid  = tid >> 6;
    const int g  = lane >> 4;      // edge group (phase1) / k-offset quad (phase2)
    const int sl = lane & 15;      // col-chunk (phase1) / A-row (phase2)
    const int rowT = blockIdx.x * 32;
    const int nodeBase = rowT + wid * 8;

    // row_start window for this wave's 8 nodes (one load, distribute by shfl)
    int rs = 0;
    if (lane < 9) {
        int idx = nodeBase + lane;
        rs = row_start[idx <= n ? idx : n];
    }

    // ---- phase 1: aggregate 8 nodes into LDS ----
    for (int nd = 0; nd < 8; ++nd) {
        if (nodeBase + nd >= n) break;           // wave-uniform
        int beg = __shfl(rs, nd, 64);
        int end = __shfl(rs, nd + 1, 64);
        float acc[8];
#pragma unroll
        for (int k = 0; k < 8; ++k) acc[k] = 0.f;
        for (int t = beg; t < end; t += 16) {
            int i0 = t + g, i1 = t + 4 + g, i2 = t + 8 + g, i3 = t + 12 + g;
            unsigned int p0 = (i0 < end) ? perm4[i0] : 0;   // p=0 -> src 0, w=+0
            unsigned int p1 = (i1 < end) ? perm4[i1] : 0;
            unsigned int p2 = (i2 < end) ? perm4[i2] : 0;
            unsigned int p3 = (i3 < end) ? perm4[i3] : 0;
            int s0 = p0 & 0xFFFF, s1 = p1 & 0xFFFF, s2 = p2 & 0xFFFF, s3 = p3 & 0xFFFF;
            uint4 v0 = *(const uint4*)(h + (size_t)s0 * DIM + sl * 8);
            uint4 v1 = *(const uint4*)(h + (size_t)s1 * DIM + sl * 8);
            uint4 v2 = *(const uint4*)(h + (size_t)s2 * DIM + sl * 8);
            uint4 v3 = *(const uint4*)(h + (size_t)s3 * DIM + sl * 8);
            float w0 = __half2float(__ushort_as_half((unsigned short)(p0 >> 16)));
            float w1 = __half2float(__ushort_as_half((unsigned short)(p1 >> 16)));
            float w2 = __half2float(__ushort_as_half((unsigned short)(p2 >> 16)));
            float w3 = __half2float(__ushort_as_half((unsigned short)(p3 >> 16)));
            acc[0] += w0 * bflo(v0.x); acc[1] += w0 * bfhi(v0.x);
            acc[2] += w0 * bflo(v0.y); acc[3] += w0 * bfhi(v0.y);
            acc[4] += w0 * bflo(v0.z); acc[5] += w0 * bfhi(v0.z);
            acc[6] += w0 * bflo(v0.w); acc[7] += w0 * bfhi(v0.w);
            acc[0] += w1 * bflo(v1.x); acc[1] += w1 * bfhi(v1.x);
            acc[2] += w1 * bflo(v1.y); acc[3] += w1 * bfhi(v1.y);
            acc[4] += w1 * bflo(v1.z); acc[5] += w1 * bfhi(v1.z);
            acc[6] += w1 * bflo(v1.w); acc[7] += w1 * bfhi(v1.w);
            acc[0] += w2 * bflo(v2.x); acc[1] += w2 * bfhi(v2.x);
            acc[2] += w2 * bflo(v2.y); acc[3] += w2 * bfhi(v2.y);
            acc[4] += w2 * bflo(v2.z); acc[5] += w2 * bfhi(v2.z);
            acc[6] += w2 * bflo(v2.w); acc[7] += w2 * bfhi(v2.w);
            acc[0] += w3 * bflo(v3.x); acc[1] += w3 * bfhi(v3.x);
            acc[2] += w3 * bflo(v3.y); acc[3] += w3 * bfhi(v3.y);
            acc[4] += w3 * bflo(v3.z); acc[5] += w3 * bfhi(v3.z);
            acc[6] += w3 * bflo(v3.w); acc[7] += w3 * bfhi(v3.w);
        }
#pragma unroll
        for (int k = 0; k < 8; ++k) {
            acc[k] += __shfl_xor(acc[k], 16, 64);
            acc[k] += __shfl_xor(acc[k], 32, 64);
        }
        if (lane < 16) {
            uint4 r;
            r.x = (unsigned int)f2bf(acc[0]) | ((unsigned int)f2bf(acc[1]) << 16);
            r.y = (unsigned int)f2bf(acc[2]) | ((unsigned int)f2bf(acc[3]) << 16);
            r.z = (unsigned int)f2bf(acc[4]) | ((unsigned int)f2bf(acc[5]) << 16);
            r.w = (unsigned int)f2bf(acc[6]) | ((unsigned int)f2bf(acc[7]) << 16);
            *(uint4*)(&Gs[(wid * 8 + nd) * LDSROW + sl * 8]) = r;
        }
    }
    __syncthreads();   // waves now read row-groups written by other waves

    // ---- phase 2: wave w -> row-group rg (16 rows) x col-half ch (64 cols) ----
    const int rg = wid >> 1;
    const int ch = wid & 1;
    floatx4 acc2[4];
#pragma unroll
    for (int ct = 0; ct < 4; ++ct) acc2[ct] = (floatx4){0.f, 0.f, 0.f, 0.f};

    int rGlob = rowT + rg * 16 + sl;
    int rr = (rGlob < n) ? rGlob : (n - 1);
    const int ko = g * 8;
#pragma unroll
    for (int t = 0; t < 8; ++t) {
        shortx8 a;
        if (t < 4)
            a = *(const shortx8*)(&Gs[(rg * 16 + sl) * LDSROW + t * 32 + ko]);
        else
            a = *(const shortx8*)(h + (size_t)rr * DIM + (t - 4) * 32 + ko);
        const unsigned short* wp = Wp + (size_t)t * 4096 + (ch * 4) * 512 + lane * 8;
#pragma unroll
        for (int ct = 0; ct < 4; ++ct) {
            shortx8 b = *(const shortx8*)(wp + ct * 512);
            acc2[ct] = __builtin_amdgcn_mfma_f32_16x16x32_bf16(a, b, acc2[ct], 0, 0, 0);
        }
    }

#pragma unroll
    for (int ct = 0; ct < 4; ++ct) {
        int col = ch * 64 + ct * 16 + sl;
        float bv = bias[col];
#pragma unroll
        for (int i = 0; i < 4; ++i) {
            int row = rowT + rg * 16 + g * 4 + i;
            if (row < n) {
                float v = acc2[ct][i] + bv;
                if (relu) v = fmaxf(v, 0.f);
                if (outF) outF[(size_t)row * DIM + col] = v;
                else      outB[(size_t)row * DIM + col] = f2bf(v);
            }
        }
    }
}

extern "C" void kernel_launch(void* const* d_in, const int* in_sizes, int n_in,
                              void* d_out, int out_size, void* d_ws, size_t ws_size,
                              hipStream_t stream) {
    const int N = N_NODES, E = N_EDGES;

    const float* x   = (const float*)d_in[0];
    const int*   ei  = (const int*)d_in[1];
    const float* ea  = (const float*)d_in[2];
    const float* wr0 = (const float*)d_in[3];
    const float* br0 = (const float*)d_in[4];
    const float* wt0 = (const float*)d_in[5];
    const float* wr1 = (const float*)d_in[6];
    const float* br1 = (const float*)d_in[7];
    const float* wt1 = (const float*)d_in[8];
    const float* wr2 = (const float*)d_in[9];
    const float* br2 = (const float*)d_in[10];
    const float* wt2 = (const float*)d_in[11];
    const int* srcI = ei;
    const int* dstI = ei + E;
    float* out = (float*)d_out;

    // workspace layout (bstage first for 8B alignment)
    int2* bstage = (int2*)d_ws;                              // NBUCK*BCAP int2 (9.6MB)
    unsigned short* X  = (unsigned short*)(bstage + (size_t)NBUCK * BCAP);  // N*128 bf16
    unsigned short* H1 = X + (size_t)N * DIM;                // N*128 bf16
    unsigned short* H2 = H1 + (size_t)N * DIM;               // N*128 bf16
    unsigned short* Wp = H2 + (size_t)N * DIM;               // 3*32768 bf16
    unsigned int* perm4 = (unsigned int*)(Wp + 3 * 32768);   // E u32
    int* bcursor = (int*)(perm4 + E);                        // NBUCK i32
    int* rowst   = bcursor + NBUCK;                          // N+1 i32

    // prep (cvt + zero + pack) and CSR build via binned counting sort
    prep_kernel<<<CVT_BLOCKS + 1 + 384, 256, 0, stream>>>(x, X, wr0, wt0, wr1, wt1, wr2, wt2, Wp, bcursor);
    partition_kernel<<<(E + CHUNK - 1) / CHUNK, 256, 0, stream>>>(srcI, dstI, ea, bcursor, bstage, E);
    bucket_fill_kernel<<<NBUCK, 256, 0, stream>>>(bstage, bcursor, rowst, perm4, N);

    const int fusedGrid = (N + 31) / 32;     // 1563 blocks, 32 rows each

    // ping-pong h buffers: gathers read prev layer, writes go to a new buffer
    fused_layer<<<fusedGrid, 256, 0, stream>>>(X,  rowst, perm4, Wp,         br0, nullptr, H1, N, 1);
    fused_layer<<<fusedGrid, 256, 0, stream>>>(H1, rowst, perm4, Wp + 32768, br1, nullptr, H2, N, 1);
    fused_layer<<<fusedGrid, 256, 0, stream>>>(H2, rowst, perm4, Wp + 65536, br2, out, nullptr, N, 0);
}

// Round 9
// 249.754 us; speedup vs baseline: 1.1804x; 1.0416x over previous
//
#include <hip/hip_runtime.h>
#include <hip/hip_bf16.h>
#include <hip/hip_fp16.h>

#define N_NODES 50000
#define N_EDGES 800000
#define DIM 128

#define NBUCK 196      // ceil(N/256) buckets of 256 consecutive dst nodes
#define BCAP  6144     // per-bucket staging capacity (mean 4096, sigma 64)
#define CHUNK 2048     // edges per partition block (391 blocks)

#define CVT_BLOCKS 25000   // 25000*256 == N_NODES*DIM exactly

#define LDSROW 136     // Gs row stride in shorts (272 B: 2-way bank alias = free)

typedef float floatx4 __attribute__((ext_vector_type(4)));
typedef short shortx8 __attribute__((ext_vector_type(8)));

__device__ __forceinline__ unsigned short f2bf(float f) {
    union { float f; unsigned int u; } c; c.f = f;
    unsigned int u = c.u;
    unsigned int r = (u + 0x7FFFu + ((u >> 16) & 1u)) >> 16;
    return (unsigned short)r;
}
__device__ __forceinline__ float bflo(unsigned int p) {
    union { unsigned int u; float f; } c; c.u = p << 16; return c.f;
}
__device__ __forceinline__ float bfhi(unsigned int p) {
    union { unsigned int u; float f; } c; c.u = p & 0xFFFF0000u; return c.f;
}

// ---------------------------------------------------------------------------
// prep: fused  x->bf16 convert | zero bcursor | weight pack
__global__ __launch_bounds__(256)
void prep_kernel(const float* __restrict__ x, unsigned short* __restrict__ X,
                 const float* __restrict__ wr0, const float* __restrict__ wt0,
                 const float* __restrict__ wr1, const float* __restrict__ wt1,
                 const float* __restrict__ wr2, const float* __restrict__ wt2,
                 unsigned short* __restrict__ Wp, int* __restrict__ bcursor) {
    int b = blockIdx.x;
    if (b < CVT_BLOCKS) {
        int i = b * 256 + threadIdx.x;       // N*DIM is an exact multiple
        X[i] = f2bf(x[i]);
    } else if (b == CVT_BLOCKS) {
        if (threadIdx.x < NBUCK) bcursor[threadIdx.x] = 0;
    } else {
        int id = (b - CVT_BLOCKS - 1) * 256 + threadIdx.x;   // < 3*32768
        int layer = id >> 15;
        int rem = id & 32767;
        int j  = rem & 7;
        int L  = (rem >> 3) & 63;
        int ct = (rem >> 9) & 7;
        int t  = rem >> 12;
        int k = t * 32 + (L >> 4) * 8 + j;
        int c = ct * 16 + (L & 15);
        const float* wr = (layer == 0) ? wr0 : (layer == 1) ? wr1 : wr2;
        const float* wt = (layer == 0) ? wt0 : (layer == 1) ? wt1 : wt2;
        float v = (k < 128) ? wr[k * 128 + c] : wt[(k - 128) * 128 + c];
        Wp[id] = f2bf(v);
    }
}

// Pass 1: bin edges by bucket (dst>>8) through LDS, contiguous runs to staging.
// CHUNK=2048 -> 391 blocks (~1.5/CU) for parallelism; run len ~10 entries.
__global__ __launch_bounds__(256)
void partition_kernel(const int* __restrict__ src, const int* __restrict__ dst,
                      const float* __restrict__ ew,
                      int* __restrict__ bcursor, int2* __restrict__ bstage, int e) {
    __shared__ int2 stage[CHUNK];      // 16 KB
    __shared__ int cnt[NBUCK];
    __shared__ int lbase[NBUCK];
    __shared__ int gbase[NBUCK];
    __shared__ int wsum[4];
    const int tid = threadIdx.x;
    const int e0 = blockIdx.x * CHUNK;
    const int ecnt = min(CHUNK, e - e0);

    for (int i = tid; i < NBUCK; i += 256) cnt[i] = 0;
    __syncthreads();
    for (int i = tid; i < ecnt; i += 256)
        atomicAdd(&cnt[dst[e0 + i] >> 8], 1);
    __syncthreads();

    {
        int v = (tid < NBUCK) ? cnt[tid] : 0;
        int lane = tid & 63, wid = tid >> 6;
        int acc = v;
#pragma unroll
        for (int off = 1; off < 64; off <<= 1) {
            int t = __shfl_up(acc, off, 64);
            if (lane >= off) acc += t;
        }
        if (lane == 63) wsum[wid] = acc;
        __syncthreads();
        int wpref = 0;
        for (int w = 0; w < wid; ++w) wpref += wsum[w];
        int excl = wpref + acc - v;
        if (tid < NBUCK) {
            lbase[tid] = excl;
            gbase[tid] = atomicAdd(&bcursor[tid], v);
            cnt[tid] = 0;            // reuse as local cursor
        }
    }
    __syncthreads();

    for (int i = tid; i < ecnt; i += 256) {
        int d = dst[e0 + i];
        int s = src[e0 + i];
        unsigned int hw = (unsigned int)__half_as_ushort(__float2half(ew[e0 + i]));
        int b = d >> 8;
        int pos = atomicAdd(&cnt[b], 1);
        stage[lbase[b] + pos] = make_int2((int)((hw << 16) | (unsigned int)s), d);
    }
    __syncthreads();

    for (int j = tid; j < ecnt; j += 256) {
        int2 p = stage[j];
        int b = p.y >> 8;
        int gidx = b * BCAP + gbase[b] + (j - lbase[b]);
        bstage[gidx] = p;
    }
}

// Pass 2: per bucket — in-block scan of bucket totals, per-node counts,
// row_start, then scatter DIRECTLY into the block-private perm4 window
// (16 KB, same-XCD lines -> L2 combines; no LDS round-trip).
__global__ __launch_bounds__(256)
void bucket_fill_kernel(const int2* __restrict__ bstage, const int* __restrict__ bcursor,
                        int* __restrict__ row_start, unsigned int* __restrict__ perm4, int n) {
    __shared__ int cnt256[256];
    __shared__ int curs[256];
    __shared__ int wsum[4];
    __shared__ int sbase, scnt;
    const int tid = threadIdx.x;
    const int b = blockIdx.x;
    const int node0 = b << 8;
    const int lane = tid & 63, wid = tid >> 6;

    {
        int v = (tid < NBUCK) ? bcursor[tid] : 0;
        int acc = v;
#pragma unroll
        for (int off = 1; off < 64; off <<= 1) {
            int t = __shfl_up(acc, off, 64);
            if (lane >= off) acc += t;
        }
        if (lane == 63) wsum[wid] = acc;
        __syncthreads();
        int wpref = 0;
        for (int w = 0; w < wid; ++w) wpref += wsum[w];
        int excl = wpref + acc - v;
        if (tid == b) { sbase = excl; scnt = v; }
    }
    __syncthreads();
    const int cntb = scnt;
    const int base = sbase;
    const int2* sp = bstage + (size_t)b * BCAP;

    cnt256[tid] = 0;
    __syncthreads();
    for (int i = tid; i < cntb; i += 256)
        atomicAdd(&cnt256[sp[i].y & 255], 1);
    __syncthreads();

    int v = cnt256[tid];
    int acc = v;
#pragma unroll
    for (int off = 1; off < 64; off <<= 1) {
        int t = __shfl_up(acc, off, 64);
        if (lane >= off) acc += t;
    }
    if (lane == 63) wsum[wid] = acc;
    __syncthreads();
    int wpref = 0;
    for (int w = 0; w < wid; ++w) wpref += wsum[w];
    int excl = wpref + acc - v;
    int node = node0 + tid;
    if (node <= n) row_start[node] = base + excl;
    curs[tid] = excl;
    __syncthreads();

    for (int i = tid; i < cntb; i += 256) {
        int2 p = sp[i];
        int pos = atomicAdd(&curs[p.y & 255], 1);
        perm4[base + pos] = (unsigned int)p.x;
    }
}

// ---------------------------------------------------------------------------
// Fused layer v3: block = 16 rows, 256 threads (4 waves), ONE barrier.
// Phase 1: wave w aggregates 4 nodes [rowT+4w, rowT+4w+4) into LDS rows
//          (4 edges in parallel: group g=lane>>4, lane reads 16B of row).
//          12500 waves total (~49/CU available) to hide gather latency.
// Phase 2: all waves share the 16 LDS rows; wave w computes cols [32w,32w+32)
//          (2 MFMA col-tiles x 8 K-steps). A from LDS (t<4) / h global (t>=4).
__global__ __launch_bounds__(256, 8)
void fused_layer(const unsigned short* __restrict__ h, const int* __restrict__ row_start,
                 const unsigned int* __restrict__ perm4, const unsigned short* __restrict__ Wp,
                 const float* __restrict__ bias, float* __restrict__ outF,
                 unsigned short* __restrict__ outB, int n, int relu) {
    __shared__ unsigned short Gs[16 * LDSROW];   // 4.25 KB
    const int tid  = threadIdx.x;
    const int lane = tid & 63;
    const int wid  = tid >> 6;
    const int g  = lane >> 4;      // edge group (phase1) / k-offset quad (phase2)
    const int sl = lane & 15;      // col-chunk (phase1) / A-row (phase2)
    const int rowT = blockIdx.x * 16;
    const int nodeBase = rowT + wid * 4;

    // row_start window for this wave's 4 nodes (one load, distribute by shfl)
    int rs = 0;
    if (lane < 5) {
        int idx = nodeBase + lane;
        rs = row_start[idx <= n ? idx : n];
    }

    // ---- phase 1: aggregate 4 nodes into LDS ----
    for (int nd = 0; nd < 4; ++nd) {
        if (nodeBase + nd >= n) break;           // wave-uniform
        int beg = __shfl(rs, nd, 64);
        int end = __shfl(rs, nd + 1, 64);
        float acc[8];
#pragma unroll
        for (int k = 0; k < 8; ++k) acc[k] = 0.f;
        for (int t = beg; t < end; t += 16) {
            int i0 = t + g, i1 = t + 4 + g, i2 = t + 8 + g, i3 = t + 12 + g;
            unsigned int p0 = (i0 < end) ? perm4[i0] : 0;   // p=0 -> src 0, w=+0
            unsigned int p1 = (i1 < end) ? perm4[i1] : 0;
            unsigned int p2 = (i2 < end) ? perm4[i2] : 0;
            unsigned int p3 = (i3 < end) ? perm4[i3] : 0;
            int s0 = p0 & 0xFFFF, s1 = p1 & 0xFFFF, s2 = p2 & 0xFFFF, s3 = p3 & 0xFFFF;
            uint4 v0 = *(const uint4*)(h + (size_t)s0 * DIM + sl * 8);
            uint4 v1 = *(const uint4*)(h + (size_t)s1 * DIM + sl * 8);
            uint4 v2 = *(const uint4*)(h + (size_t)s2 * DIM + sl * 8);
            uint4 v3 = *(const uint4*)(h + (size_t)s3 * DIM + sl * 8);
            float w0 = __half2float(__ushort_as_half((unsigned short)(p0 >> 16)));
            float w1 = __half2float(__ushort_as_half((unsigned short)(p1 >> 16)));
            float w2 = __half2float(__ushort_as_half((unsigned short)(p2 >> 16)));
            float w3 = __half2float(__ushort_as_half((unsigned short)(p3 >> 16)));
            acc[0] += w0 * bflo(v0.x); acc[1] += w0 * bfhi(v0.x);
            acc[2] += w0 * bflo(v0.y); acc[3] += w0 * bfhi(v0.y);
            acc[4] += w0 * bflo(v0.z); acc[5] += w0 * bfhi(v0.z);
            acc[6] += w0 * bflo(v0.w); acc[7] += w0 * bfhi(v0.w);
            acc[0] += w1 * bflo(v1.x); acc[1] += w1 * bfhi(v1.x);
            acc[2] += w1 * bflo(v1.y); acc[3] += w1 * bfhi(v1.y);
            acc[4] += w1 * bflo(v1.z); acc[5] += w1 * bfhi(v1.z);
            acc[6] += w1 * bflo(v1.w); acc[7] += w1 * bfhi(v1.w);
            acc[0] += w2 * bflo(v2.x); acc[1] += w2 * bfhi(v2.x);
            acc[2] += w2 * bflo(v2.y); acc[3] += w2 * bfhi(v2.y);
            acc[4] += w2 * bflo(v2.z); acc[5] += w2 * bfhi(v2.z);
            acc[6] += w2 * bflo(v2.w); acc[7] += w2 * bfhi(v2.w);
            acc[0] += w3 * bflo(v3.x); acc[1] += w3 * bfhi(v3.x);
            acc[2] += w3 * bflo(v3.y); acc[3] += w3 * bfhi(v3.y);
            acc[4] += w3 * bflo(v3.z); acc[5] += w3 * bfhi(v3.z);
            acc[6] += w3 * bflo(v3.w); acc[7] += w3 * bfhi(v3.w);
        }
#pragma unroll
        for (int k = 0; k < 8; ++k) {
            acc[k] += __shfl_xor(acc[k], 16, 64);
            acc[k] += __shfl_xor(acc[k], 32, 64);
        }
        if (lane < 16) {
            uint4 r;
            r.x = (unsigned int)f2bf(acc[0]) | ((unsigned int)f2bf(acc[1]) << 16);
            r.y = (unsigned int)f2bf(acc[2]) | ((unsigned int)f2bf(acc[3]) << 16);
            r.z = (unsigned int)f2bf(acc[4]) | ((unsigned int)f2bf(acc[5]) << 16);
            r.w = (unsigned int)f2bf(acc[6]) | ((unsigned int)f2bf(acc[7]) << 16);
            *(uint4*)(&Gs[(wid * 4 + nd) * LDSROW + sl * 8]) = r;
        }
    }
    __syncthreads();   // waves now read rows written by other waves

    // ---- phase 2: wave w -> 16 rows x cols [32w, 32w+32) ----
    floatx4 acc2[2];
#pragma unroll
    for (int ct = 0; ct < 2; ++ct) acc2[ct] = (floatx4){0.f, 0.f, 0.f, 0.f};

    int rGlob = rowT + sl;
    int rr = (rGlob < n) ? rGlob : (n - 1);
    const int ko = g * 8;
#pragma unroll
    for (int t = 0; t < 8; ++t) {
        shortx8 a;
        if (t < 4)
            a = *(const shortx8*)(&Gs[sl * LDSROW + t * 32 + ko]);
        else
            a = *(const shortx8*)(h + (size_t)rr * DIM + (t - 4) * 32 + ko);
        const unsigned short* wp = Wp + (size_t)t * 4096 + (wid * 2) * 512 + lane * 8;
#pragma unroll
        for (int ct = 0; ct < 2; ++ct) {
            shortx8 b = *(const shortx8*)(wp + ct * 512);
            acc2[ct] = __builtin_amdgcn_mfma_f32_16x16x32_bf16(a, b, acc2[ct], 0, 0, 0);
        }
    }

#pragma unroll
    for (int ct = 0; ct < 2; ++ct) {
        int col = wid * 32 + ct * 16 + sl;
        float bv = bias[col];
#pragma unroll
        for (int i = 0; i < 4; ++i) {
            int row = rowT + g * 4 + i;
            if (row < n) {
                float v = acc2[ct][i] + bv;
                if (relu) v = fmaxf(v, 0.f);
                if (outF) outF[(size_t)row * DIM + col] = v;
                else      outB[(size_t)row * DIM + col] = f2bf(v);
            }
        }
    }
}

extern "C" void kernel_launch(void* const* d_in, const int* in_sizes, int n_in,
                              void* d_out, int out_size, void* d_ws, size_t ws_size,
                              hipStream_t stream) {
    const int N = N_NODES, E = N_EDGES;

    const float* x   = (const float*)d_in[0];
    const int*   ei  = (const int*)d_in[1];
    const float* ea  = (const float*)d_in[2];
    const float* wr0 = (const float*)d_in[3];
    const float* br0 = (const float*)d_in[4];
    const float* wt0 = (const float*)d_in[5];
    const float* wr1 = (const float*)d_in[6];
    const float* br1 = (const float*)d_in[7];
    const float* wt1 = (const float*)d_in[8];
    const float* wr2 = (const float*)d_in[9];
    const float* br2 = (const float*)d_in[10];
    const float* wt2 = (const float*)d_in[11];
    const int* srcI = ei;
    const int* dstI = ei + E;
    float* out = (float*)d_out;

    // workspace layout (bstage first for 8B alignment)
    int2* bstage = (int2*)d_ws;                              // NBUCK*BCAP int2 (9.6MB)
    unsigned short* X  = (unsigned short*)(bstage + (size_t)NBUCK * BCAP);  // N*128 bf16
    unsigned short* H1 = X + (size_t)N * DIM;                // N*128 bf16
    unsigned short* H2 = H1 + (size_t)N * DIM;               // N*128 bf16
    unsigned short* Wp = H2 + (size_t)N * DIM;               // 3*32768 bf16
    unsigned int* perm4 = (unsigned int*)(Wp + 3 * 32768);   // E u32
    int* bcursor = (int*)(perm4 + E);                        // NBUCK i32
    int* rowst   = bcursor + NBUCK;                          // N+1 i32

    // prep (cvt + zero + pack) and CSR build via binned counting sort
    prep_kernel<<<CVT_BLOCKS + 1 + 384, 256, 0, stream>>>(x, X, wr0, wt0, wr1, wt1, wr2, wt2, Wp, bcursor);
    partition_kernel<<<(E + CHUNK - 1) / CHUNK, 256, 0, stream>>>(srcI, dstI, ea, bcursor, bstage, E);
    bucket_fill_kernel<<<NBUCK, 256, 0, stream>>>(bstage, bcursor, rowst, perm4, N);

    const int fusedGrid = (N + 15) / 16;     // 3125 blocks, 16 rows each

    // ping-pong h buffers: gathers read prev layer, writes go to a new buffer
    fused_layer<<<fusedGrid, 256, 0, stream>>>(X,  rowst, perm4, Wp,         br0, nullptr, H1, N, 1);
    fused_layer<<<fusedGrid, 256, 0, stream>>>(H1, rowst, perm4, Wp + 32768, br1, nullptr, H2, N, 1);
    fused_layer<<<fusedGrid, 256, 0, stream>>>(H2, rowst, perm4, Wp + 65536, br2, out, nullptr, N, 0);
}

// Round 10
// 245.802 us; speedup vs baseline: 1.1994x; 1.0161x over previous
//
#include <hip/hip_runtime.h>
#include <hip/hip_bf16.h>
#include <hip/hip_fp16.h>

#define N_NODES 50000
#define N_EDGES 800000
#define DIM 128

#define NBUCK 391      // ceil(N/128) buckets of 128 consecutive dst nodes
#define BCAP  2816     // per-bucket staging capacity (mean 2046, sigma 45 -> +17 sigma)
#define CHUNK 2048     // edges per partition block (391 blocks x 512 thr)

#define CVT_BLOCKS 25000   // 25000*256 == N_NODES*DIM exactly

#define LDSROW 136     // Gs row stride in shorts (272 B: 2-way bank alias = free)

typedef float floatx4 __attribute__((ext_vector_type(4)));
typedef float floatx2 __attribute__((ext_vector_type(2)));
typedef short shortx8 __attribute__((ext_vector_type(8)));

__device__ __forceinline__ unsigned short f2bf(float f) {
    union { float f; unsigned int u; } c; c.f = f;
    unsigned int u = c.u;
    unsigned int r = (u + 0x7FFFu + ((u >> 16) & 1u)) >> 16;
    return (unsigned short)r;
}
// unpack u32 (2 bf16) -> packed float2 (feeds v_pk_fma_f32)
__device__ __forceinline__ floatx2 bf2x2(unsigned int p) {
    union { unsigned int u; float f; } lo, hi;
    lo.u = p << 16; hi.u = p & 0xFFFF0000u;
    return (floatx2){lo.f, hi.f};
}

// ---------------------------------------------------------------------------
// prep: fused  x->bf16 convert | zero bcursor | weight pack
__global__ __launch_bounds__(256)
void prep_kernel(const float* __restrict__ x, unsigned short* __restrict__ X,
                 const float* __restrict__ wr0, const float* __restrict__ wt0,
                 const float* __restrict__ wr1, const float* __restrict__ wt1,
                 const float* __restrict__ wr2, const float* __restrict__ wt2,
                 unsigned short* __restrict__ Wp, int* __restrict__ bcursor) {
    int b = blockIdx.x;
    if (b < CVT_BLOCKS) {
        int i = b * 256 + threadIdx.x;       // N*DIM is an exact multiple
        X[i] = f2bf(x[i]);
    } else if (b == CVT_BLOCKS) {
        for (int i = threadIdx.x; i < NBUCK; i += 256) bcursor[i] = 0;
    } else {
        int id = (b - CVT_BLOCKS - 1) * 256 + threadIdx.x;   // < 3*32768
        int layer = id >> 15;
        int rem = id & 32767;
        int j  = rem & 7;
        int L  = (rem >> 3) & 63;
        int ct = (rem >> 9) & 7;
        int t  = rem >> 12;
        int k = t * 32 + (L >> 4) * 8 + j;
        int c = ct * 16 + (L & 15);
        const float* wr = (layer == 0) ? wr0 : (layer == 1) ? wr1 : wr2;
        const float* wt = (layer == 0) ? wt0 : (layer == 1) ? wt1 : wt2;
        float v = (k < 128) ? wr[k * 128 + c] : wt[(k - 128) * 128 + c];
        Wp[id] = f2bf(v);
    }
}

// Pass 1: bin edges by bucket (dst>>7) through LDS, contiguous runs to staging.
// 512 threads so the 391-entry scan is single-pass.
__global__ __launch_bounds__(512)
void partition_kernel(const int* __restrict__ src, const int* __restrict__ dst,
                      const float* __restrict__ ew,
                      int* __restrict__ bcursor, int2* __restrict__ bstage, int e) {
    __shared__ int2 stage[CHUNK];      // 16 KB
    __shared__ int cnt[NBUCK];
    __shared__ int lbase[NBUCK];
    __shared__ int gbase[NBUCK];
    __shared__ int wsum[8];
    const int tid = threadIdx.x;
    const int e0 = blockIdx.x * CHUNK;
    const int ecnt = min(CHUNK, e - e0);

    for (int i = tid; i < NBUCK; i += 512) cnt[i] = 0;
    __syncthreads();
    for (int i = tid; i < ecnt; i += 512)
        atomicAdd(&cnt[dst[e0 + i] >> 7], 1);
    __syncthreads();

    {
        int v = (tid < NBUCK) ? cnt[tid] : 0;
        int lane = tid & 63, wid = tid >> 6;
        int acc = v;
#pragma unroll
        for (int off = 1; off < 64; off <<= 1) {
            int t = __shfl_up(acc, off, 64);
            if (lane >= off) acc += t;
        }
        if (lane == 63) wsum[wid] = acc;
        __syncthreads();
        int wpref = 0;
        for (int w = 0; w < wid; ++w) wpref += wsum[w];
        int excl = wpref + acc - v;
        if (tid < NBUCK) {
            lbase[tid] = excl;
            gbase[tid] = atomicAdd(&bcursor[tid], v);
            cnt[tid] = 0;            // reuse as local cursor
        }
    }
    __syncthreads();

    for (int i = tid; i < ecnt; i += 512) {
        int d = dst[e0 + i];
        int s = src[e0 + i];
        unsigned int hw = (unsigned int)__half_as_ushort(__float2half(ew[e0 + i]));
        int b = d >> 7;
        int pos = atomicAdd(&cnt[b], 1);
        stage[lbase[b] + pos] = make_int2((int)((hw << 16) | (unsigned int)s), d);
    }
    __syncthreads();

    for (int j = tid; j < ecnt; j += 512) {
        int2 p = stage[j];
        int b = p.y >> 7;
        int gidx = b * BCAP + gbase[b] + (j - lbase[b]);
        bstage[gidx] = p;
    }
}

// Pass 2: per bucket (128 nodes, 391 blocks) — in-block scan of bucket totals
// (2 entries/thread), per-node counts, row_start, direct scatter into the
// block-private perm4 window (~8 KB, same-XCD lines -> L2 combines).
__global__ __launch_bounds__(256)
void bucket_fill_kernel(const int2* __restrict__ bstage, const int* __restrict__ bcursor,
                        int* __restrict__ row_start, unsigned int* __restrict__ perm4, int n) {
    __shared__ int cnt128[128];
    __shared__ int curs[128];
    __shared__ int wsum[4];
    __shared__ int sbase, scnt;
    const int tid = threadIdx.x;
    const int b = blockIdx.x;
    const int node0 = b << 7;
    const int lane = tid & 63, wid = tid >> 6;

    // exclusive prefix over 391 bucket totals, 2 entries per thread
    {
        int i0 = tid * 2, i1 = tid * 2 + 1;
        int v0 = (i0 < NBUCK) ? bcursor[i0] : 0;
        int v1 = (i1 < NBUCK) ? bcursor[i1] : 0;
        int s = v0 + v1;
        int acc = s;
#pragma unroll
        for (int off = 1; off < 64; off <<= 1) {
            int t = __shfl_up(acc, off, 64);
            if (lane >= off) acc += t;
        }
        if (lane == 63) wsum[wid] = acc;
        __syncthreads();
        int wpref = 0;
        for (int w = 0; w < wid; ++w) wpref += wsum[w];
        int excl = wpref + acc - s;
        if (i0 == b) { sbase = excl;      scnt = v0; }
        if (i1 == b) { sbase = excl + v0; scnt = v1; }
    }
    __syncthreads();
    const int cntb = scnt;
    const int base = sbase;
    const int2* sp = bstage + (size_t)b * BCAP;

    if (tid < 128) cnt128[tid] = 0;
    __syncthreads();
    for (int i = tid; i < cntb; i += 256)
        atomicAdd(&cnt128[sp[i].y & 127], 1);
    __syncthreads();

    // scan 128 per-node counts (first 2 waves carry data)
    int v = (tid < 128) ? cnt128[tid] : 0;
    int acc = v;
#pragma unroll
    for (int off = 1; off < 64; off <<= 1) {
        int t = __shfl_up(acc, off, 64);
        if (lane >= off) acc += t;
    }
    if (lane == 63) wsum[wid] = acc;
    __syncthreads();
    int wpref = 0;
    for (int w = 0; w < wid; ++w) wpref += wsum[w];
    int excl = wpref + acc - v;
    if (tid < 128) {
        int node = node0 + tid;
        if (node <= n) row_start[node] = base + excl;
        curs[tid] = excl;
    }
    __syncthreads();

    for (int i = tid; i < cntb; i += 256) {
        int2 p = sp[i];
        int pos = atomicAdd(&curs[p.y & 127], 1);
        perm4[base + pos] = (unsigned int)p.x;
    }
}

// ---------------------------------------------------------------------------
// Fused layer v4: block = 16 rows, 256 threads (4 waves), ONE barrier.
// Phase 1: wave w aggregates 4 nodes into LDS rows; accumulation in packed
//          float2 (v_pk_fma_f32) — 12 instr/edge/lane vs 16 scalar.
// Phase 2: all waves share the 16 LDS rows; wave w computes cols [32w,32w+32).
__global__ __launch_bounds__(256, 8)
void fused_layer(const unsigned short* __restrict__ h, const int* __restrict__ row_start,
                 const unsigned int* __restrict__ perm4, const unsigned short* __restrict__ Wp,
                 const float* __restrict__ bias, float* __restrict__ outF,
                 unsigned short* __restrict__ outB, int n, int relu) {
    __shared__ unsigned short Gs[16 * LDSROW];   // 4.25 KB
    const int tid  = threadIdx.x;
    const int lane = tid & 63;
    const int wid  = tid >> 6;
    const int g  = lane >> 4;      // edge group (phase1) / k-offset quad (phase2)
    const int sl = lane & 15;      // col-chunk (phase1) / A-row (phase2)
    const int rowT = blockIdx.x * 16;
    const int nodeBase = rowT + wid * 4;

    // row_start window for this wave's 4 nodes (one load, distribute by shfl)
    int rs = 0;
    if (lane < 5) {
        int idx = nodeBase + lane;
        rs = row_start[idx <= n ? idx : n];
    }

    // ---- phase 1: aggregate 4 nodes into LDS ----
    for (int nd = 0; nd < 4; ++nd) {
        if (nodeBase + nd >= n) break;           // wave-uniform
        int beg = __shfl(rs, nd, 64);
        int end = __shfl(rs, nd + 1, 64);
        floatx2 ac[4];
#pragma unroll
        for (int k = 0; k < 4; ++k) ac[k] = (floatx2){0.f, 0.f};
        for (int t = beg; t < end; t += 16) {
            int i0 = t + g, i1 = t + 4 + g, i2 = t + 8 + g, i3 = t + 12 + g;
            unsigned int p0 = (i0 < end) ? perm4[i0] : 0;   // p=0 -> src 0, w=+0
            unsigned int p1 = (i1 < end) ? perm4[i1] : 0;
            unsigned int p2 = (i2 < end) ? perm4[i2] : 0;
            unsigned int p3 = (i3 < end) ? perm4[i3] : 0;
            int s0 = p0 & 0xFFFF, s1 = p1 & 0xFFFF, s2 = p2 & 0xFFFF, s3 = p3 & 0xFFFF;
            uint4 v0 = *(const uint4*)(h + (size_t)s0 * DIM + sl * 8);
            uint4 v1 = *(const uint4*)(h + (size_t)s1 * DIM + sl * 8);
            uint4 v2 = *(const uint4*)(h + (size_t)s2 * DIM + sl * 8);
            uint4 v3 = *(const uint4*)(h + (size_t)s3 * DIM + sl * 8);
            float w0 = __half2float(__ushort_as_half((unsigned short)(p0 >> 16)));
            float w1 = __half2float(__ushort_as_half((unsigned short)(p1 >> 16)));
            float w2 = __half2float(__ushort_as_half((unsigned short)(p2 >> 16)));
            float w3 = __half2float(__ushort_as_half((unsigned short)(p3 >> 16)));
            floatx2 W0 = (floatx2){w0, w0}, W1 = (floatx2){w1, w1};
            floatx2 W2 = (floatx2){w2, w2}, W3 = (floatx2){w3, w3};
            ac[0] += W0 * bf2x2(v0.x); ac[1] += W0 * bf2x2(v0.y);
            ac[2] += W0 * bf2x2(v0.z); ac[3] += W0 * bf2x2(v0.w);
            ac[0] += W1 * bf2x2(v1.x); ac[1] += W1 * bf2x2(v1.y);
            ac[2] += W1 * bf2x2(v1.z); ac[3] += W1 * bf2x2(v1.w);
            ac[0] += W2 * bf2x2(v2.x); ac[1] += W2 * bf2x2(v2.y);
            ac[2] += W2 * bf2x2(v2.z); ac[3] += W2 * bf2x2(v2.w);
            ac[0] += W3 * bf2x2(v3.x); ac[1] += W3 * bf2x2(v3.y);
            ac[2] += W3 * bf2x2(v3.z); ac[3] += W3 * bf2x2(v3.w);
        }
        float acc[8] = {ac[0].x, ac[0].y, ac[1].x, ac[1].y,
                        ac[2].x, ac[2].y, ac[3].x, ac[3].y};
#pragma unroll
        for (int k = 0; k < 8; ++k) {
            acc[k] += __shfl_xor(acc[k], 16, 64);
            acc[k] += __shfl_xor(acc[k], 32, 64);
        }
        if (lane < 16) {
            uint4 r;
            r.x = (unsigned int)f2bf(acc[0]) | ((unsigned int)f2bf(acc[1]) << 16);
            r.y = (unsigned int)f2bf(acc[2]) | ((unsigned int)f2bf(acc[3]) << 16);
            r.z = (unsigned int)f2bf(acc[4]) | ((unsigned int)f2bf(acc[5]) << 16);
            r.w = (unsigned int)f2bf(acc[6]) | ((unsigned int)f2bf(acc[7]) << 16);
            *(uint4*)(&Gs[(wid * 4 + nd) * LDSROW + sl * 8]) = r;
        }
    }
    __syncthreads();   // waves now read rows written by other waves

    // ---- phase 2: wave w -> 16 rows x cols [32w, 32w+32) ----
    floatx4 acc2[2];
#pragma unroll
    for (int ct = 0; ct < 2; ++ct) acc2[ct] = (floatx4){0.f, 0.f, 0.f, 0.f};

    int rGlob = rowT + sl;
    int rr = (rGlob < n) ? rGlob : (n - 1);
    const int ko = g * 8;
#pragma unroll
    for (int t = 0; t < 8; ++t) {
        shortx8 a;
        if (t < 4)
            a = *(const shortx8*)(&Gs[sl * LDSROW + t * 32 + ko]);
        else
            a = *(const shortx8*)(h + (size_t)rr * DIM + (t - 4) * 32 + ko);
        const unsigned short* wp = Wp + (size_t)t * 4096 + (wid * 2) * 512 + lane * 8;
#pragma unroll
        for (int ct = 0; ct < 2; ++ct) {
            shortx8 b = *(const shortx8*)(wp + ct * 512);
            acc2[ct] = __builtin_amdgcn_mfma_f32_16x16x32_bf16(a, b, acc2[ct], 0, 0, 0);
        }
    }

#pragma unroll
    for (int ct = 0; ct < 2; ++ct) {
        int col = wid * 32 + ct * 16 + sl;
        float bv = bias[col];
#pragma unroll
        for (int i = 0; i < 4; ++i) {
            int row = rowT + g * 4 + i;
            if (row < n) {
                float v = acc2[ct][i] + bv;
                if (relu) v = fmaxf(v, 0.f);
                if (outF) outF[(size_t)row * DIM + col] = v;
                else      outB[(size_t)row * DIM + col] = f2bf(v);
            }
        }
    }
}

extern "C" void kernel_launch(void* const* d_in, const int* in_sizes, int n_in,
                              void* d_out, int out_size, void* d_ws, size_t ws_size,
                              hipStream_t stream) {
    const int N = N_NODES, E = N_EDGES;

    const float* x   = (const float*)d_in[0];
    const int*   ei  = (const int*)d_in[1];
    const float* ea  = (const float*)d_in[2];
    const float* wr0 = (const float*)d_in[3];
    const float* br0 = (const float*)d_in[4];
    const float* wt0 = (const float*)d_in[5];
    const float* wr1 = (const float*)d_in[6];
    const float* br1 = (const float*)d_in[7];
    const float* wt1 = (const float*)d_in[8];
    const float* wr2 = (const float*)d_in[9];
    const float* br2 = (const float*)d_in[10];
    const float* wt2 = (const float*)d_in[11];
    const int* srcI = ei;
    const int* dstI = ei + E;
    float* out = (float*)d_out;

    // workspace layout (bstage first for 8B alignment)
    int2* bstage = (int2*)d_ws;                              // NBUCK*BCAP int2 (8.8MB)
    unsigned short* X  = (unsigned short*)(bstage + (size_t)NBUCK * BCAP);  // N*128 bf16
    unsigned short* H1 = X + (size_t)N * DIM;                // N*128 bf16
    unsigned short* H2 = H1 + (size_t)N * DIM;               // N*128 bf16
    unsigned short* Wp = H2 + (size_t)N * DIM;               // 3*32768 bf16
    unsigned int* perm4 = (unsigned int*)(Wp + 3 * 32768);   // E u32
    int* bcursor = (int*)(perm4 + E);                        // NBUCK i32
    int* rowst   = bcursor + NBUCK;                          // N+1 i32

    // prep (cvt + zero + pack) and CSR build via binned counting sort
    prep_kernel<<<CVT_BLOCKS + 1 + 384, 256, 0, stream>>>(x, X, wr0, wt0, wr1, wt1, wr2, wt2, Wp, bcursor);
    partition_kernel<<<(E + CHUNK - 1) / CHUNK, 512, 0, stream>>>(srcI, dstI, ea, bcursor, bstage, E);
    bucket_fill_kernel<<<NBUCK, 256, 0, stream>>>(bstage, bcursor, rowst, perm4, N);

    const int fusedGrid = (N + 15) / 16;     // 3125 blocks, 16 rows each

    // ping-pong h buffers: gathers read prev layer, writes go to a new buffer
    fused_layer<<<fusedGrid, 256, 0, stream>>>(X,  rowst, perm4, Wp,         br0, nullptr, H1, N, 1);
    fused_layer<<<fusedGrid, 256, 0, stream>>>(H1, rowst, perm4, Wp + 32768, br1, nullptr, H2, N, 1);
    fused_layer<<<fusedGrid, 256, 0, stream>>>(H2, rowst, perm4, Wp + 65536, br2, out, nullptr, N, 0);
}